// Round 14
// baseline (481.173 us; speedup 1.0000x reference)
//
#include <hip/hip_runtime.h>
#include <hip/hip_cooperative_groups.h>
#include <stdint.h>
#include <stddef.h>

namespace cg = cooperative_groups;

// Problem constants (from reference): B=8, L=8192, D=1024, M=L/4=2048.
// Setup guarantees exactly M true mask positions per row -> counts == M.
#define B_ 8
#define L_ 8192
#define D_ 1024
#define M_ 2048
#define D4_ (D_/4)
#define TROWS_ 64            // rows per tile (carry + stream granularity)
#define NTILE_ (L_/TROWS_)   // 128 tiles per batch row
#define NBLK_ (B_*NTILE_)    // 1024 blocks

typedef float f4 __attribute__((ext_vector_type(4)));

// ---------------- workspace layout (bytes) ----------------
#define OFF_POS    ((size_t)0)
#define OFF_DEC    (OFF_POS  + (size_t)B_*M_*4)
#define OFF_A      (OFF_DEC  + (size_t)B_*M_*4)              // float A[B][NTILE]
#define OFF_CIT    (OFF_A    + (size_t)B_*NTILE_*4)          // int ci_tile[B][NTILE]
#define OFF_EZ     (OFF_CIT  + (size_t)B_*NTILE_*4)          // float ez[B][NTILE][D]
#define OFF_HINIT  (OFF_EZ   + (size_t)B_*NTILE_*D_*4)       // float hinit[B][NTILE][D]
#define WS_TOTAL   (OFF_HINIT + (size_t)B_*NTILE_*D_*4)

// ============================================================================
// Cooperative mega-kernel: all 4 phases, inter-phase data via global ws only
// (no registers live across grid.sync -> no R6-style spill). The per-tile
// boundary list lives in LDS and is reused by phases 1 and 3.
// ============================================================================
__global__ __launch_bounds__(256, 4)
void mega_kernel(const f4* __restrict__ x4,
                 const f4* __restrict__ res4,
                 const float* __restrict__ prob,
                 const void* __restrict__ mask_raw,
                 const float* __restrict__ state,
                 int* __restrict__ pos,
                 float* __restrict__ dec,
                 float* __restrict__ Aseg,
                 int* __restrict__ ci_tile,
                 float* __restrict__ ez,
                 float* __restrict__ hinit,
                 f4* __restrict__ out4,
                 float* __restrict__ newstate) {
    cg::grid_group grid = cg::this_grid();
    const int blk = blockIdx.x;
    const int t = threadIdx.x;

    __shared__ int   u8flag;
    __shared__ int   wsum[4];
    __shared__ int   woff[4];
    __shared__ int   pl[TROWS_ + 2];
    __shared__ float dl[TROWS_ + 2];
    __shared__ float Al[NTILE_];

    // ---------------- phase 0: compact (blocks 0..7, 32 l per thread) -------
    if (blk < B_) {
        const int b = blk;
        if (t == 0) u8flag = 0;
        __syncthreads();
        {
            const uint32_t* mu = (const uint32_t*)mask_raw;
            uint32_t orv = 0;
            #pragma unroll
            for (int j = 0; j < 8; j++) orv |= mu[t * 8 + j];
            if (orv > 1u) atomicOr(&u8flag, 1);
        }
        __syncthreads();
        const bool u8 = (u8flag != 0);

        const int base_l = t * 32;
        int cnt = 0;
        if (u8) {
            const uint8_t* mrow = (const uint8_t*)mask_raw + (size_t)b * L_;
            #pragma unroll
            for (int j = 0; j < 32; j++) cnt += mrow[base_l + j] ? 1 : 0;
        } else {
            const int* mrow = (const int*)mask_raw + (size_t)b * L_;
            #pragma unroll
            for (int j = 0; j < 32; j++) cnt += mrow[base_l + j] ? 1 : 0;
        }
        const int lane = t & 63, wid = t >> 6;
        int v = cnt;
        #pragma unroll
        for (int off = 1; off < 64; off <<= 1) {
            int n = __shfl_up(v, off, 64);
            if (lane >= off) v += n;
        }
        if (lane == 63) wsum[wid] = v;
        __syncthreads();
        if (t < 4) {
            int acc = 0;
            for (int w = 0; w < t; w++) acc += wsum[w];
            woff[t] = acc;
        }
        __syncthreads();
        int run = (v - cnt) + woff[wid];

        const float* prow = prob + (size_t)b * L_;
        if (u8) {
            const uint8_t* mrow = (const uint8_t*)mask_raw + (size_t)b * L_;
            for (int j = 0; j < 32; j++) {
                const int l = base_l + j;
                if (mrow[l]) {
                    float d = fminf(fmaxf(1.0f - prow[l], 0.0f), 1.0f);
                    pos[(size_t)b * M_ + run] = l;
                    dec[(size_t)b * M_ + run] = d;
                    run++;
                }
            }
        } else {
            const int* mrow = (const int*)mask_raw + (size_t)b * L_;
            for (int j = 0; j < 32; j++) {
                const int l = base_l + j;
                if (mrow[l]) {
                    float d = fminf(fmaxf(1.0f - prow[l], 0.0f), 1.0f);
                    pos[(size_t)b * M_ + run] = l;
                    dec[(size_t)b * M_ + run] = d;
                    run++;
                }
            }
        }
        // thread t ends at l = 32t+31; tile k starts at 64k: boundary after
        // odd threads -> k = (t+1)/2; ci_tile[k] = run-1 (chunks <= 64k-1).
        if (t & 1) {
            const int k = (t + 1) >> 1;
            if (k < NTILE_) ci_tile[b * NTILE_ + k] = run - 1;
        }
        __threadfence();
    }
    grid.sync();

    // ---------------- phase 1: per-tile zero-init scan end + decay product --
    const int b = blk >> 7;              // NTILE_ = 128
    const int k = blk & (NTILE_ - 1);
    const int m0 = (k == 0) ? -1 : ci_tile[b * NTILE_ + k];
    const int mhi = (k == NTILE_ - 1) ? (M_ - 1) : ci_tile[b * NTILE_ + k + 1];
    const int n = mhi - m0;              // #chunks in tile, 0..64

    if (t < TROWS_ + 2) {
        const int mm = m0 + 1 + t;
        if (mm < M_) {
            pl[t] = pos[(size_t)b * M_ + mm];
            dl[t] = dec[(size_t)b * M_ + mm];
        } else {
            pl[t] = L_;                  // sentinel
            dl[t] = 1.0f;
        }
    }
    __syncthreads();

    const f4* xrow = x4 + (size_t)b * L_ * D4_;
    {
        f4 h = (f4)(0.0f);
        float A = 1.0f;
        for (int g = 0; g < n; g += 8) {
            f4    xv[8];
            float dd[8];
            #pragma unroll
            for (int j = 0; j < 8; j++) {
                const int mm = g + j;
                const int mc = (mm < n) ? mm : 0;
                dd[j] = (mm < n) ? dl[mc] : 1.0f;
                xv[j] = xrow[(size_t)pl[mc] * D4_ + t];
            }
            #pragma unroll
            for (int j = 0; j < 8; j++) {
                h = dd[j] * h + (1.0f - dd[j]) * xv[j];
                A *= dd[j];
            }
        }
        ((f4*)ez)[(size_t)blk * D4_ + t] = h;
        if (t == 0) Aseg[blk] = A;
    }
    __threadfence();
    grid.sync();

    // ---------------- phase 2: carry scan across tiles (blocks 0..31) -------
    if (blk < 32) {
        const int b2 = blk >> 2;
        const int ch = ((blk & 3) << 8) + t;    // scalar channel 0..1023
        for (int i = t; i < NTILE_; i += 256) Al[i] = Aseg[b2 * NTILE_ + i];
        __syncthreads();
        float c = state[(size_t)b2 * D_ + ch];
        for (int s0 = 0; s0 < NTILE_; s0 += 8) {
            float e[8];
            #pragma unroll
            for (int j = 0; j < 8; j++)
                e[j] = ez[((size_t)b2 * NTILE_ + s0 + j) * D_ + ch];
            #pragma unroll
            for (int j = 0; j < 8; j++) {
                hinit[((size_t)b2 * NTILE_ + s0 + j) * D_ + ch] = c;
                c = fmaf(Al[s0 + j], c, e[j]);
            }
        }
        newstate[(size_t)b2 * D_ + ch] = c;     // counts == M guaranteed
        __threadfence();
    }
    grid.sync();

    // ---------------- phase 3: pure-stream fused scan + scatter (R12 body) --
    const int l0 = k * TROWS_;
    f4 h = ((const f4*)hinit)[(size_t)blk * D4_ + t];
    float live = (m0 >= 0) ? 1.0f : 0.0f;

    const f4* resrow = res4 + (size_t)b * L_ * D4_;
    f4*       outrow = out4 + (size_t)b * L_ * D4_;

    int mi = 0;
    int nextb = pl[0];
    int a0 = (pl[0] < L_) ? pl[0] : 0;
    int a1 = (pl[1] < L_) ? pl[1] : 0;
    f4 xn  = xrow[(size_t)a0 * D4_ + t];
    f4 xn2 = xrow[(size_t)a1 * D4_ + t];
    int l = l0;

    #define ADV(K, HH, LV)                                                \
        if (l + (K) == nextb) {                                           \
            const float d_ = dl[mi];                                      \
            h = d_ * h + (1.0f - d_) * xn;                                \
            live = 1.0f;                                                  \
            xn = xn2;                                                     \
            ++mi;                                                         \
            nextb = pl[mi];                                               \
            const int nr_ = (pl[mi + 1] < L_) ? pl[mi + 1] : 0;           \
            xn2 = xrow[(size_t)nr_ * D4_ + t];                            \
        }                                                                 \
        HH = h; LV = live;

    f4 c0, c1, c2, c3;
    c0 = __builtin_nontemporal_load(resrow + (size_t)(l + 0) * D4_ + t);
    c1 = __builtin_nontemporal_load(resrow + (size_t)(l + 1) * D4_ + t);
    c2 = __builtin_nontemporal_load(resrow + (size_t)(l + 2) * D4_ + t);
    c3 = __builtin_nontemporal_load(resrow + (size_t)(l + 3) * D4_ + t);
    for (int g = 0; g < (TROWS_ / 4) - 1; ++g) {
        f4 n0 = __builtin_nontemporal_load(resrow + (size_t)(l + 4) * D4_ + t);
        f4 n1 = __builtin_nontemporal_load(resrow + (size_t)(l + 5) * D4_ + t);
        f4 n2 = __builtin_nontemporal_load(resrow + (size_t)(l + 6) * D4_ + t);
        f4 n3 = __builtin_nontemporal_load(resrow + (size_t)(l + 7) * D4_ + t);
        f4 h0, h1, h2, h3;
        float v0, v1, v2, v3;
        ADV(0, h0, v0); ADV(1, h1, v1); ADV(2, h2, v2); ADV(3, h3, v3);
        __builtin_nontemporal_store(c0 + v0 * h0, outrow + (size_t)(l + 0) * D4_ + t);
        __builtin_nontemporal_store(c1 + v1 * h1, outrow + (size_t)(l + 1) * D4_ + t);
        __builtin_nontemporal_store(c2 + v2 * h2, outrow + (size_t)(l + 2) * D4_ + t);
        __builtin_nontemporal_store(c3 + v3 * h3, outrow + (size_t)(l + 3) * D4_ + t);
        c0 = n0; c1 = n1; c2 = n2; c3 = n3;
        l += 4;
    }
    {
        f4 h0, h1, h2, h3;
        float v0, v1, v2, v3;
        ADV(0, h0, v0); ADV(1, h1, v1); ADV(2, h2, v2); ADV(3, h3, v3);
        __builtin_nontemporal_store(c0 + v0 * h0, outrow + (size_t)(l + 0) * D4_ + t);
        __builtin_nontemporal_store(c1 + v1 * h1, outrow + (size_t)(l + 1) * D4_ + t);
        __builtin_nontemporal_store(c2 + v2 * h2, outrow + (size_t)(l + 2) * D4_ + t);
        __builtin_nontemporal_store(c3 + v3 * h3, outrow + (size_t)(l + 3) * D4_ + t);
    }
    #undef ADV
}

// ============================================================================
// Fallback path: verified R12 4-kernel pipeline (used if coop launch fails).
// ============================================================================
__global__ __launch_bounds__(1024)
void compact_kernel(const void* __restrict__ mask_raw,
                    const float* __restrict__ prob,
                    int* __restrict__ pos,
                    float* __restrict__ dec,
                    int* __restrict__ ci_tile) {
    const int b = blockIdx.x;
    const int t = threadIdx.x;
    __shared__ int u8flag;
    if (t == 0) u8flag = 0;
    __syncthreads();
    {
        const uint32_t* mu = (const uint32_t*)mask_raw;
        uint32_t w0 = mu[t * 2], w1 = mu[t * 2 + 1];
        if (w0 > 1u || w1 > 1u) atomicOr(&u8flag, 1);
    }
    __syncthreads();
    const bool u8 = (u8flag != 0);
    int mv[8];
    const int base_l = t * 8;
    if (u8) {
        const uint8_t* mrow = (const uint8_t*)mask_raw + (size_t)b * L_;
        #pragma unroll
        for (int j = 0; j < 8; j++) mv[j] = mrow[base_l + j] ? 1 : 0;
    } else {
        const int* mrow = (const int*)mask_raw + (size_t)b * L_;
        #pragma unroll
        for (int j = 0; j < 8; j++) mv[j] = mrow[base_l + j] ? 1 : 0;
    }
    int tsum = 0;
    #pragma unroll
    for (int j = 0; j < 8; j++) tsum += mv[j];
    const int lane = t & 63, wid = t >> 6;
    int v = tsum;
    #pragma unroll
    for (int off = 1; off < 64; off <<= 1) {
        int n = __shfl_up(v, off, 64);
        if (lane >= off) v += n;
    }
    __shared__ int wsum[16];
    __shared__ int woff[16];
    if (lane == 63) wsum[wid] = v;
    __syncthreads();
    if (t < 16) {
        int acc = 0;
        for (int w = 0; w < t; w++) acc += wsum[w];
        woff[t] = acc;
    }
    __syncthreads();
    int run = (v - tsum) + woff[wid];
    const float* prow = prob + (size_t)b * L_;
    #pragma unroll
    for (int j = 0; j < 8; j++) {
        const int l = base_l + j;
        if (mv[j]) {
            float d = fminf(fmaxf(1.0f - prow[l], 0.0f), 1.0f);
            pos[(size_t)b * M_ + run] = l;
            dec[(size_t)b * M_ + run] = d;
            run += 1;
        }
    }
    if ((t & 7) == 7) {
        const int k = (t + 1) >> 3;
        if (k < NTILE_) ci_tile[b * NTILE_ + k] = run - 1;
    }
}

__global__ __launch_bounds__(256)
void segend_kernel(const f4* __restrict__ x4,
                   const int* __restrict__ pos,
                   const float* __restrict__ dec,
                   const int* __restrict__ ci_tile,
                   f4* __restrict__ ez4,
                   float* __restrict__ Aseg) {
    const int blk = blockIdx.x;
    const int b = blk >> 7;
    const int k = blk & (NTILE_ - 1);
    const int t = threadIdx.x;
    const int mlo = (k == 0) ? 0 : ci_tile[b * NTILE_ + k] + 1;
    const int mhi = (k == NTILE_ - 1) ? (M_ - 1) : ci_tile[b * NTILE_ + k + 1];
    const int n = mhi - mlo + 1;
    __shared__ int   pl[TROWS_];
    __shared__ float dl[TROWS_];
    if (t < n) {
        pl[t] = pos[(size_t)b * M_ + mlo + t];
        dl[t] = dec[(size_t)b * M_ + mlo + t];
    }
    __syncthreads();
    f4 h = (f4)(0.0f);
    float A = 1.0f;
    if (n > 0) {
        const f4* xrow = x4 + (size_t)b * L_ * D4_;
        for (int g = 0; g < n; g += 8) {
            f4    xv[8];
            float dd[8];
            #pragma unroll
            for (int j = 0; j < 8; j++) {
                const int mm = g + j;
                const int mc = (mm < n) ? mm : 0;
                dd[j] = (mm < n) ? dl[mc] : 1.0f;
                xv[j] = xrow[(size_t)pl[mc] * D4_ + t];
            }
            #pragma unroll
            for (int j = 0; j < 8; j++) {
                h = dd[j] * h + (1.0f - dd[j]) * xv[j];
                A *= dd[j];
            }
        }
    }
    ez4[(size_t)blk * D4_ + t] = h;
    if (t == 0) Aseg[blk] = A;
}

__global__ __launch_bounds__(64)
void combine_kernel(const float* __restrict__ ez,
                    const float* __restrict__ Aseg,
                    const float* __restrict__ state,
                    float* __restrict__ hinit,
                    float* __restrict__ newstate) {
    const int b = blockIdx.x;
    const int ch = blockIdx.y * 64 + threadIdx.x;
    __shared__ float Al[NTILE_];
    for (int i = threadIdx.x; i < NTILE_; i += 64) Al[i] = Aseg[b * NTILE_ + i];
    __syncthreads();
    float c = state[(size_t)b * D_ + ch];
    for (int s0 = 0; s0 < NTILE_; s0 += 8) {
        float e[8];
        #pragma unroll
        for (int j = 0; j < 8; j++)
            e[j] = ez[((size_t)b * NTILE_ + s0 + j) * D_ + ch];
        #pragma unroll
        for (int j = 0; j < 8; j++) {
            hinit[((size_t)b * NTILE_ + s0 + j) * D_ + ch] = c;
            c = fmaf(Al[s0 + j], c, e[j]);
        }
    }
    newstate[(size_t)b * D_ + ch] = c;
}

__global__ __launch_bounds__(256)
void fused_kernel(const f4* __restrict__ x4,
                  const f4* __restrict__ res4,
                  const int* __restrict__ pos,
                  const float* __restrict__ dec,
                  const int* __restrict__ ci_tile,
                  const f4* __restrict__ hinit4,
                  f4* __restrict__ out4) {
    const int blk = blockIdx.x;
    const int b = blk >> 7;
    const int k = blk & (NTILE_ - 1);
    const int t = threadIdx.x;
    const int l0 = k * TROWS_;
    const int m0 = (k == 0) ? -1 : ci_tile[b * NTILE_ + k];
    __shared__ int   pl[TROWS_ + 2];
    __shared__ float dl[TROWS_ + 2];
    if (t < TROWS_ + 2) {
        const int mm = m0 + 1 + t;
        if (mm < M_) {
            pl[t] = pos[(size_t)b * M_ + mm];
            dl[t] = dec[(size_t)b * M_ + mm];
        } else {
            pl[t] = L_;
            dl[t] = 1.0f;
        }
    }
    __syncthreads();
    const f4* xrow = x4 + (size_t)b * L_ * D4_;
    f4 h = hinit4[(size_t)blk * D4_ + t];
    float live = (m0 >= 0) ? 1.0f : 0.0f;
    const f4* resrow = res4 + (size_t)b * L_ * D4_;
    f4*       outrow = out4 + (size_t)b * L_ * D4_;
    int mi = 0;
    int nextb = pl[0];
    int a0 = (pl[0] < L_) ? pl[0] : 0;
    int a1 = (pl[1] < L_) ? pl[1] : 0;
    f4 xn  = xrow[(size_t)a0 * D4_ + t];
    f4 xn2 = xrow[(size_t)a1 * D4_ + t];
    int l = l0;
    #define ADV(K, HH, LV)                                                \
        if (l + (K) == nextb) {                                           \
            const float d_ = dl[mi];                                      \
            h = d_ * h + (1.0f - d_) * xn;                                \
            live = 1.0f;                                                  \
            xn = xn2;                                                     \
            ++mi;                                                         \
            nextb = pl[mi];                                               \
            const int nr_ = (pl[mi + 1] < L_) ? pl[mi + 1] : 0;           \
            xn2 = xrow[(size_t)nr_ * D4_ + t];                            \
        }                                                                 \
        HH = h; LV = live;
    f4 c0, c1, c2, c3;
    c0 = __builtin_nontemporal_load(resrow + (size_t)(l + 0) * D4_ + t);
    c1 = __builtin_nontemporal_load(resrow + (size_t)(l + 1) * D4_ + t);
    c2 = __builtin_nontemporal_load(resrow + (size_t)(l + 2) * D4_ + t);
    c3 = __builtin_nontemporal_load(resrow + (size_t)(l + 3) * D4_ + t);
    for (int g = 0; g < (TROWS_ / 4) - 1; ++g) {
        f4 n0 = __builtin_nontemporal_load(resrow + (size_t)(l + 4) * D4_ + t);
        f4 n1 = __builtin_nontemporal_load(resrow + (size_t)(l + 5) * D4_ + t);
        f4 n2 = __builtin_nontemporal_load(resrow + (size_t)(l + 6) * D4_ + t);
        f4 n3 = __builtin_nontemporal_load(resrow + (size_t)(l + 7) * D4_ + t);
        f4 h0, h1, h2, h3;
        float v0, v1, v2, v3;
        ADV(0, h0, v0); ADV(1, h1, v1); ADV(2, h2, v2); ADV(3, h3, v3);
        __builtin_nontemporal_store(c0 + v0 * h0, outrow + (size_t)(l + 0) * D4_ + t);
        __builtin_nontemporal_store(c1 + v1 * h1, outrow + (size_t)(l + 1) * D4_ + t);
        __builtin_nontemporal_store(c2 + v2 * h2, outrow + (size_t)(l + 2) * D4_ + t);
        __builtin_nontemporal_store(c3 + v3 * h3, outrow + (size_t)(l + 3) * D4_ + t);
        c0 = n0; c1 = n1; c2 = n2; c3 = n3;
        l += 4;
    }
    {
        f4 h0, h1, h2, h3;
        float v0, v1, v2, v3;
        ADV(0, h0, v0); ADV(1, h1, v1); ADV(2, h2, v2); ADV(3, h3, v3);
        __builtin_nontemporal_store(c0 + v0 * h0, outrow + (size_t)(l + 0) * D4_ + t);
        __builtin_nontemporal_store(c1 + v1 * h1, outrow + (size_t)(l + 1) * D4_ + t);
        __builtin_nontemporal_store(c2 + v2 * h2, outrow + (size_t)(l + 2) * D4_ + t);
        __builtin_nontemporal_store(c3 + v3 * h3, outrow + (size_t)(l + 3) * D4_ + t);
    }
    #undef ADV
}

extern "C" void kernel_launch(void* const* d_in, const int* in_sizes, int n_in,
                              void* d_out, int out_size, void* d_ws, size_t ws_size,
                              hipStream_t stream) {
    const float* x        = (const float*)d_in[0];
    const float* residual = (const float*)d_in[1];
    const float* prob     = (const float*)d_in[2];
    const void*  mask     = d_in[3];
    const float* state    = (const float*)d_in[4];

    float* out       = (float*)d_out;                       // (B,L,D)
    float* new_state = out + (size_t)B_ * L_ * D_;          // (B,D)

    if (ws_size < WS_TOTAL) return;  // fail loudly (zeros) rather than corrupt

    char* ws = (char*)d_ws;
    int*   pos     = (int*)  (ws + OFF_POS);
    float* dec     = (float*)(ws + OFF_DEC);
    float* Aseg    = (float*)(ws + OFF_A);
    int*   ci_tile = (int*)  (ws + OFF_CIT);
    float* ez      = (float*)(ws + OFF_EZ);
    float* hinit   = (float*)(ws + OFF_HINIT);

    const f4* x4   = (const f4*)x;
    const f4* res4 = (const f4*)residual;
    f4*       out4 = (f4*)out;

    void* args[] = {
        (void*)&x4, (void*)&res4, (void*)&prob, (void*)&mask, (void*)&state,
        (void*)&pos, (void*)&dec, (void*)&Aseg, (void*)&ci_tile,
        (void*)&ez, (void*)&hinit, (void*)&out4, (void*)&new_state
    };
    hipError_t err = hipLaunchCooperativeKernel(
        (const void*)mega_kernel, dim3(NBLK_), dim3(256), args, 0, stream);

    if (err != hipSuccess) {
        // fallback: verified R12 pipeline
        compact_kernel<<<B_, 1024, 0, stream>>>(mask, prob, pos, dec, ci_tile);
        segend_kernel<<<B_ * NTILE_, 256, 0, stream>>>(x4, pos, dec, ci_tile, (f4*)ez, Aseg);
        combine_kernel<<<dim3(B_, 16), 64, 0, stream>>>(ez, Aseg, state, hinit, new_state);
        fused_kernel<<<B_ * NTILE_, 256, 0, stream>>>(x4, res4, pos, dec, ci_tile, (const f4*)hinit, out4);
    }
}

// Round 15
// 126.835 us; speedup vs baseline: 3.7937x; 3.7937x over previous
//
#include <hip/hip_runtime.h>
#include <stdint.h>
#include <stddef.h>

// Problem constants (from reference): B=8, L=8192, D=1024, M=L/4=2048.
// Setup guarantees exactly M true mask positions per row -> counts == M.
#define B_ 8
#define L_ 8192
#define D_ 1024
#define M_ 2048
#define D4_ (D_/4)
#define TROWS_ 128           // rows per tile (carry + stream granularity)
#define NTILE_ (L_/TROWS_)   // 64 tiles per batch row
#define NBLK_ (B_*NTILE_)    // 512 blocks

typedef float f4 __attribute__((ext_vector_type(4)));

// ---------------- workspace layout (bytes) ----------------
#define OFF_POS    ((size_t)0)
#define OFF_DEC    (OFF_POS  + (size_t)B_*M_*4)
#define OFF_A      (OFF_DEC  + (size_t)B_*M_*4)              // float A[B][NTILE]
#define OFF_CIT    (OFF_A    + (size_t)B_*NTILE_*4)          // int ci_tile[B][NTILE]
#define OFF_EZ     (OFF_CIT  + (size_t)B_*NTILE_*4)          // float ez[B][NTILE][D]
#define OFF_HINIT  (OFF_EZ   + (size_t)B_*NTILE_*D_*4)       // float hinit[B][NTILE][D]
#define WS_TOTAL   (OFF_HINIT + (size_t)B_*NTILE_*D_*4)

// ---------------- kernel 1: per-row compaction (prefix sum over mask) -------
// One block (1024 threads) per batch row; thread t owns l = 8t..8t+7.
// Also emits ci_tile[b][k] = ci[128k-1] (chunk index active entering tile k).
// Mask dtype (u8 bool vs int32) detected in-block from the first 8 KiB.
__global__ __launch_bounds__(1024)
void compact_kernel(const void* __restrict__ mask_raw,
                    const float* __restrict__ prob,
                    int* __restrict__ pos,
                    float* __restrict__ dec,
                    int* __restrict__ ci_tile) {
    const int b = blockIdx.x;
    const int t = threadIdx.x;

    __shared__ int u8flag;
    if (t == 0) u8flag = 0;
    __syncthreads();
    {
        const uint32_t* mu = (const uint32_t*)mask_raw;
        uint32_t w0 = mu[t * 2], w1 = mu[t * 2 + 1];
        if (w0 > 1u || w1 > 1u) atomicOr(&u8flag, 1);
    }
    __syncthreads();
    const bool u8 = (u8flag != 0);

    int mv[8];
    const int base_l = t * 8;
    if (u8) {
        const uint8_t* mrow = (const uint8_t*)mask_raw + (size_t)b * L_;
        #pragma unroll
        for (int j = 0; j < 8; j++) mv[j] = mrow[base_l + j] ? 1 : 0;
    } else {
        const int* mrow = (const int*)mask_raw + (size_t)b * L_;
        #pragma unroll
        for (int j = 0; j < 8; j++) mv[j] = mrow[base_l + j] ? 1 : 0;
    }
    int tsum = 0;
    #pragma unroll
    for (int j = 0; j < 8; j++) tsum += mv[j];

    // block-wide exclusive scan of per-thread sums (wave64 x 16 waves)
    const int lane = t & 63, wid = t >> 6;
    int v = tsum;
    #pragma unroll
    for (int off = 1; off < 64; off <<= 1) {
        int n = __shfl_up(v, off, 64);
        if (lane >= off) v += n;
    }
    __shared__ int wsum[16];
    __shared__ int woff[16];
    if (lane == 63) wsum[wid] = v;
    __syncthreads();
    if (t < 16) {
        int acc = 0;
        for (int w = 0; w < t; w++) acc += wsum[w];
        woff[t] = acc;
    }
    __syncthreads();
    int run = (v - tsum) + woff[wid];   // exclusive prefix for this thread

    const float* prow = prob + (size_t)b * L_;
    #pragma unroll
    for (int j = 0; j < 8; j++) {
        const int l = base_l + j;
        if (mv[j]) {
            float d = 1.0f - prow[l];
            d = fminf(fmaxf(d, 0.0f), 1.0f);
            pos[(size_t)b * M_ + run] = l;
            dec[(size_t)b * M_ + run] = d;
            run += 1;
        }
    }
    // after l = 8t+7: run = #chunks with pos <= 8t+7. Tile k starts at
    // l0 = 128k = 8(t+1) when (t+1)%16 == 0 -> ci_tile[k] = run-1.
    if ((t & 15) == 15) {
        const int k = (t + 1) >> 4;
        if (k < NTILE_) ci_tile[b * NTILE_ + k] = run - 1;
    }
}

// ---------------- kernel 2: per-TILE zero-init scan end + decay product -----
// One block per (b, tile k): scans the tile's chunk range
// [mlo, mhi] = [ci_tile[k]+1, ci_tile[k+1]] (<= 128 chunks). Gathers batched
// 8-wide so loads pipeline.
__global__ __launch_bounds__(256)
void segend_kernel(const f4* __restrict__ x4,
                   const int* __restrict__ pos,
                   const float* __restrict__ dec,
                   const int* __restrict__ ci_tile,
                   f4* __restrict__ ez4,
                   float* __restrict__ Aseg) {
    const int blk = blockIdx.x;          // b*NTILE_ + k
    const int b = blk >> 6;              // NTILE_ = 64
    const int k = blk & (NTILE_ - 1);
    const int t = threadIdx.x;

    const int mlo = (k == 0) ? 0 : ci_tile[b * NTILE_ + k] + 1;
    const int mhi = (k == NTILE_ - 1) ? (M_ - 1) : ci_tile[b * NTILE_ + k + 1];
    const int n = mhi - mlo + 1;         // 0..128

    __shared__ int   pl[TROWS_];
    __shared__ float dl[TROWS_];
    if (t < n) {
        pl[t] = pos[(size_t)b * M_ + mlo + t];
        dl[t] = dec[(size_t)b * M_ + mlo + t];
    }
    __syncthreads();

    f4 h = (f4)(0.0f);
    float A = 1.0f;
    if (n > 0) {
        const f4* xrow = x4 + (size_t)b * L_ * D4_;
        for (int g = 0; g < n; g += 8) {
            f4    xv[8];
            float dd[8];
            #pragma unroll
            for (int j = 0; j < 8; j++) {
                const int mm = g + j;
                const int mc = (mm < n) ? mm : 0;
                dd[j] = (mm < n) ? dl[mc] : 1.0f;
                xv[j] = xrow[(size_t)pl[mc] * D4_ + t];
            }
            #pragma unroll
            for (int j = 0; j < 8; j++) {
                h = dd[j] * h + (1.0f - dd[j]) * xv[j];
                A *= dd[j];
            }
        }
    }
    ez4[(size_t)blk * D4_ + t] = h;
    if (t == 0) Aseg[blk] = A;
}

// ---------------- kernel 3: carry propagation across tiles + new_state ------
// grid (B, 16), block 64: scalar channel per thread (8192 parallel chains).
// hinit[b][k] = ema state ENTERING tile k (c_0 = state). ez prefetched in
// batches of 8 so the serial FMA chain stalls once per 8 steps.
__global__ __launch_bounds__(64)
void combine_kernel(const float* __restrict__ ez,
                    const float* __restrict__ Aseg,
                    const float* __restrict__ state,
                    float* __restrict__ hinit,
                    float* __restrict__ newstate) {
    const int b = blockIdx.x;
    const int ch = blockIdx.y * 64 + threadIdx.x;   // scalar channel 0..1023
    __shared__ float Al[NTILE_];
    for (int i = threadIdx.x; i < NTILE_; i += 64) Al[i] = Aseg[b * NTILE_ + i];
    __syncthreads();

    float c = state[(size_t)b * D_ + ch];
    for (int s0 = 0; s0 < NTILE_; s0 += 8) {
        float e[8];
        #pragma unroll
        for (int j = 0; j < 8; j++)
            e[j] = ez[((size_t)b * NTILE_ + s0 + j) * D_ + ch];
        #pragma unroll
        for (int j = 0; j < 8; j++) {
            hinit[((size_t)b * NTILE_ + s0 + j) * D_ + ch] = c;
            c = fmaf(Al[s0 + j], c, e[j]);
        }
    }
    newstate[(size_t)b * D_ + ch] = c;   // counts == M guaranteed
}

// ---------------- kernel 4: PURE-STREAM fused scan + scatter ----------------
// One block (256 threads) per (b, 128-row tile). h seeded from hinit[b][k]
// (one 16B load — no prologue chain). Fixed 128-row NT pipeline (4-deep,
// R12's verified-best depth); `live` mask handles the ci<0 prefix; ADV
// advances h at chunk boundaries with double-prefetched x gathers.
__global__ __launch_bounds__(256)
void fused_kernel(const f4* __restrict__ x4,
                  const f4* __restrict__ res4,
                  const int* __restrict__ pos,
                  const float* __restrict__ dec,
                  const int* __restrict__ ci_tile,
                  const f4* __restrict__ hinit4,
                  f4* __restrict__ out4) {
    const int blk = blockIdx.x;          // b*NTILE_ + k
    const int b = blk >> 6;              // NTILE_ = 64
    const int k = blk & (NTILE_ - 1);
    const int t = threadIdx.x;
    const int l0 = k * TROWS_;

    const int m0 = (k == 0) ? -1 : ci_tile[b * NTILE_ + k];

    // boundary list for this tile: chunks m0+1 .. m0+TROWS_+1 (sentinel-padded)
    __shared__ int   pl[TROWS_ + 2];
    __shared__ float dl[TROWS_ + 2];
    for (int i = t; i < TROWS_ + 2; i += 256) {
        const int mm = m0 + 1 + i;
        if (mm < M_) {
            pl[i] = pos[(size_t)b * M_ + mm];
            dl[i] = dec[(size_t)b * M_ + mm];
        } else {
            pl[i] = L_;                  // sentinel: never matches a row
            dl[i] = 1.0f;
        }
    }
    __syncthreads();

    const f4* xrow = x4 + (size_t)b * L_ * D4_;

    f4 h = hinit4[(size_t)blk * D4_ + t];   // state entering this tile
    float live = (m0 >= 0) ? 1.0f : 0.0f;

    const f4* resrow = res4 + (size_t)b * L_ * D4_;
    f4*       outrow = out4 + (size_t)b * L_ * D4_;

    int mi = 0;
    int nextb = pl[0];
    int a0 = (pl[0] < L_) ? pl[0] : 0;
    int a1 = (pl[1] < L_) ? pl[1] : 0;
    f4 xn  = xrow[(size_t)a0 * D4_ + t];
    f4 xn2 = xrow[(size_t)a1 * D4_ + t];
    int l = l0;

    #define ADV(K, HH, LV)                                                \
        if (l + (K) == nextb) {                                           \
            const float d_ = dl[mi];                                      \
            h = d_ * h + (1.0f - d_) * xn;                                \
            live = 1.0f;                                                  \
            xn = xn2;                                                     \
            ++mi;                                                         \
            nextb = pl[mi];                                               \
            const int nr_ = (pl[mi + 1] < L_) ? pl[mi + 1] : 0;           \
            xn2 = xrow[(size_t)nr_ * D4_ + t];                            \
        }                                                                 \
        HH = h; LV = live;

    f4 c0, c1, c2, c3;
    c0 = __builtin_nontemporal_load(resrow + (size_t)(l + 0) * D4_ + t);
    c1 = __builtin_nontemporal_load(resrow + (size_t)(l + 1) * D4_ + t);
    c2 = __builtin_nontemporal_load(resrow + (size_t)(l + 2) * D4_ + t);
    c3 = __builtin_nontemporal_load(resrow + (size_t)(l + 3) * D4_ + t);
    for (int g = 0; g < (TROWS_ / 4) - 1; ++g) {
        f4 n0 = __builtin_nontemporal_load(resrow + (size_t)(l + 4) * D4_ + t);
        f4 n1 = __builtin_nontemporal_load(resrow + (size_t)(l + 5) * D4_ + t);
        f4 n2 = __builtin_nontemporal_load(resrow + (size_t)(l + 6) * D4_ + t);
        f4 n3 = __builtin_nontemporal_load(resrow + (size_t)(l + 7) * D4_ + t);
        f4 h0, h1, h2, h3;
        float v0, v1, v2, v3;
        ADV(0, h0, v0); ADV(1, h1, v1); ADV(2, h2, v2); ADV(3, h3, v3);
        __builtin_nontemporal_store(c0 + v0 * h0, outrow + (size_t)(l + 0) * D4_ + t);
        __builtin_nontemporal_store(c1 + v1 * h1, outrow + (size_t)(l + 1) * D4_ + t);
        __builtin_nontemporal_store(c2 + v2 * h2, outrow + (size_t)(l + 2) * D4_ + t);
        __builtin_nontemporal_store(c3 + v3 * h3, outrow + (size_t)(l + 3) * D4_ + t);
        c0 = n0; c1 = n1; c2 = n2; c3 = n3;
        l += 4;
    }
    {
        f4 h0, h1, h2, h3;
        float v0, v1, v2, v3;
        ADV(0, h0, v0); ADV(1, h1, v1); ADV(2, h2, v2); ADV(3, h3, v3);
        __builtin_nontemporal_store(c0 + v0 * h0, outrow + (size_t)(l + 0) * D4_ + t);
        __builtin_nontemporal_store(c1 + v1 * h1, outrow + (size_t)(l + 1) * D4_ + t);
        __builtin_nontemporal_store(c2 + v2 * h2, outrow + (size_t)(l + 2) * D4_ + t);
        __builtin_nontemporal_store(c3 + v3 * h3, outrow + (size_t)(l + 3) * D4_ + t);
    }
    #undef ADV
}

extern "C" void kernel_launch(void* const* d_in, const int* in_sizes, int n_in,
                              void* d_out, int out_size, void* d_ws, size_t ws_size,
                              hipStream_t stream) {
    const float* x        = (const float*)d_in[0];
    const float* residual = (const float*)d_in[1];
    const float* prob     = (const float*)d_in[2];
    const void*  mask     = d_in[3];
    const float* state    = (const float*)d_in[4];

    float* out       = (float*)d_out;                       // (B,L,D)
    float* new_state = out + (size_t)B_ * L_ * D_;          // (B,D)

    if (ws_size < WS_TOTAL) return;  // fail loudly (zeros) rather than corrupt

    char* ws = (char*)d_ws;
    int*   pos     = (int*)  (ws + OFF_POS);
    float* dec     = (float*)(ws + OFF_DEC);
    float* Aseg    = (float*)(ws + OFF_A);
    int*   ci_tile = (int*)  (ws + OFF_CIT);
    float* ez      = (float*)(ws + OFF_EZ);
    float* hinit   = (float*)(ws + OFF_HINIT);

    compact_kernel<<<B_, 1024, 0, stream>>>(mask, prob, pos, dec, ci_tile);

    segend_kernel<<<NBLK_, 256, 0, stream>>>(
        (const f4*)x, pos, dec, ci_tile, (f4*)ez, Aseg);

    combine_kernel<<<dim3(B_, 16), 64, 0, stream>>>(
        ez, Aseg, state, hinit, new_state);

    fused_kernel<<<NBLK_, 256, 0, stream>>>(
        (const f4*)x, (const f4*)residual, pos, dec, ci_tile,
        (const f4*)hinit, (f4*)out);
}

// Round 16
// 125.501 us; speedup vs baseline: 3.8340x; 1.0106x over previous
//
#include <hip/hip_runtime.h>
#include <stdint.h>
#include <stddef.h>

// Problem constants (from reference): B=8, L=8192, D=1024, M=L/4=2048.
// Setup guarantees exactly M true mask positions per row -> counts == M.
#define B_ 8
#define L_ 8192
#define D_ 1024
#define M_ 2048
#define D4_ (D_/4)
#define TROWS_ 256           // rows per tile (carry + stream granularity)
#define NTILE_ (L_/TROWS_)   // 32 tiles per batch row
#define NBLK_ (B_*NTILE_)    // 256 blocks (1 per CU)

typedef float f4 __attribute__((ext_vector_type(4)));

// ---------------- workspace layout (bytes) ----------------
#define OFF_POS    ((size_t)0)
#define OFF_DEC    (OFF_POS  + (size_t)B_*M_*4)
#define OFF_A      (OFF_DEC  + (size_t)B_*M_*4)              // float A[B][NTILE]
#define OFF_CIT    (OFF_A    + (size_t)B_*NTILE_*4)          // int ci_tile[B][NTILE]
#define OFF_EZ     (OFF_CIT  + (size_t)B_*NTILE_*4)          // float ez[B][NTILE][D]
#define OFF_HINIT  (OFF_EZ   + (size_t)B_*NTILE_*D_*4)       // float hinit[B][NTILE][D]
#define WS_TOTAL   (OFF_HINIT + (size_t)B_*NTILE_*D_*4)

// ---------------- kernel 1: per-row compaction (prefix sum over mask) -------
// One block (1024 threads) per batch row; thread t owns l = 8t..8t+7.
// Also emits ci_tile[b][k] = ci[256k-1] (chunk index active entering tile k).
// Mask dtype (u8 bool vs int32) detected in-block from the first 8 KiB.
__global__ __launch_bounds__(1024)
void compact_kernel(const void* __restrict__ mask_raw,
                    const float* __restrict__ prob,
                    int* __restrict__ pos,
                    float* __restrict__ dec,
                    int* __restrict__ ci_tile) {
    const int b = blockIdx.x;
    const int t = threadIdx.x;

    __shared__ int u8flag;
    if (t == 0) u8flag = 0;
    __syncthreads();
    {
        const uint32_t* mu = (const uint32_t*)mask_raw;
        uint32_t w0 = mu[t * 2], w1 = mu[t * 2 + 1];
        if (w0 > 1u || w1 > 1u) atomicOr(&u8flag, 1);
    }
    __syncthreads();
    const bool u8 = (u8flag != 0);

    int mv[8];
    const int base_l = t * 8;
    if (u8) {
        const uint8_t* mrow = (const uint8_t*)mask_raw + (size_t)b * L_;
        #pragma unroll
        for (int j = 0; j < 8; j++) mv[j] = mrow[base_l + j] ? 1 : 0;
    } else {
        const int* mrow = (const int*)mask_raw + (size_t)b * L_;
        #pragma unroll
        for (int j = 0; j < 8; j++) mv[j] = mrow[base_l + j] ? 1 : 0;
    }
    int tsum = 0;
    #pragma unroll
    for (int j = 0; j < 8; j++) tsum += mv[j];

    // block-wide exclusive scan of per-thread sums (wave64 x 16 waves)
    const int lane = t & 63, wid = t >> 6;
    int v = tsum;
    #pragma unroll
    for (int off = 1; off < 64; off <<= 1) {
        int n = __shfl_up(v, off, 64);
        if (lane >= off) v += n;
    }
    __shared__ int wsum[16];
    __shared__ int woff[16];
    if (lane == 63) wsum[wid] = v;
    __syncthreads();
    if (t < 16) {
        int acc = 0;
        for (int w = 0; w < t; w++) acc += wsum[w];
        woff[t] = acc;
    }
    __syncthreads();
    int run = (v - tsum) + woff[wid];   // exclusive prefix for this thread

    const float* prow = prob + (size_t)b * L_;
    #pragma unroll
    for (int j = 0; j < 8; j++) {
        const int l = base_l + j;
        if (mv[j]) {
            float d = 1.0f - prow[l];
            d = fminf(fmaxf(d, 0.0f), 1.0f);
            pos[(size_t)b * M_ + run] = l;
            dec[(size_t)b * M_ + run] = d;
            run += 1;
        }
    }
    // after l = 8t+7: run = #chunks with pos <= 8t+7. Tile k starts at
    // l0 = 256k = 8(t+1) when (t+1)%32 == 0 -> ci_tile[k] = run-1.
    if ((t & 31) == 31) {
        const int k = (t + 1) >> 5;
        if (k < NTILE_) ci_tile[b * NTILE_ + k] = run - 1;
    }
}

// ---------------- kernel 2: per-TILE zero-init scan end + decay product -----
// One block per (b, tile k): scans the tile's chunk range
// [mlo, mhi] = [ci_tile[k]+1, ci_tile[k+1]] (<= 256 chunks). Gathers batched
// 8-wide so loads pipeline.
__global__ __launch_bounds__(256)
void segend_kernel(const f4* __restrict__ x4,
                   const int* __restrict__ pos,
                   const float* __restrict__ dec,
                   const int* __restrict__ ci_tile,
                   f4* __restrict__ ez4,
                   float* __restrict__ Aseg) {
    const int blk = blockIdx.x;          // b*NTILE_ + k
    const int b = blk >> 5;              // NTILE_ = 32
    const int k = blk & (NTILE_ - 1);
    const int t = threadIdx.x;

    const int mlo = (k == 0) ? 0 : ci_tile[b * NTILE_ + k] + 1;
    const int mhi = (k == NTILE_ - 1) ? (M_ - 1) : ci_tile[b * NTILE_ + k + 1];
    const int n = mhi - mlo + 1;         // 0..256

    __shared__ int   pl[TROWS_];
    __shared__ float dl[TROWS_];
    if (t < n) {
        pl[t] = pos[(size_t)b * M_ + mlo + t];
        dl[t] = dec[(size_t)b * M_ + mlo + t];
    }
    __syncthreads();

    f4 h = (f4)(0.0f);
    float A = 1.0f;
    if (n > 0) {
        const f4* xrow = x4 + (size_t)b * L_ * D4_;
        for (int g = 0; g < n; g += 8) {
            f4    xv[8];
            float dd[8];
            #pragma unroll
            for (int j = 0; j < 8; j++) {
                const int mm = g + j;
                const int mc = (mm < n) ? mm : 0;
                dd[j] = (mm < n) ? dl[mc] : 1.0f;
                xv[j] = xrow[(size_t)pl[mc] * D4_ + t];
            }
            #pragma unroll
            for (int j = 0; j < 8; j++) {
                h = dd[j] * h + (1.0f - dd[j]) * xv[j];
                A *= dd[j];
            }
        }
    }
    ez4[(size_t)blk * D4_ + t] = h;
    if (t == 0) Aseg[blk] = A;
}

// ---------------- kernel 3: carry propagation across tiles + new_state ------
// grid (B, 16), block 64: scalar channel per thread (8192 parallel chains).
// hinit[b][k] = ema state ENTERING tile k (c_0 = state). ez prefetched in
// batches of 8 so the serial FMA chain stalls once per 8 steps.
__global__ __launch_bounds__(64)
void combine_kernel(const float* __restrict__ ez,
                    const float* __restrict__ Aseg,
                    const float* __restrict__ state,
                    float* __restrict__ hinit,
                    float* __restrict__ newstate) {
    const int b = blockIdx.x;
    const int ch = blockIdx.y * 64 + threadIdx.x;   // scalar channel 0..1023
    __shared__ float Al[NTILE_];
    if (threadIdx.x < NTILE_) Al[threadIdx.x] = Aseg[b * NTILE_ + threadIdx.x];
    __syncthreads();

    float c = state[(size_t)b * D_ + ch];
    for (int s0 = 0; s0 < NTILE_; s0 += 8) {
        float e[8];
        #pragma unroll
        for (int j = 0; j < 8; j++)
            e[j] = ez[((size_t)b * NTILE_ + s0 + j) * D_ + ch];
        #pragma unroll
        for (int j = 0; j < 8; j++) {
            hinit[((size_t)b * NTILE_ + s0 + j) * D_ + ch] = c;
            c = fmaf(Al[s0 + j], c, e[j]);
        }
    }
    newstate[(size_t)b * D_ + ch] = c;   // counts == M guaranteed
}

// ---------------- kernel 4: PURE-STREAM fused scan + scatter (8-deep) -------
// One block (256 threads) per (b, 256-row tile). h seeded from hinit[b][k]
// (one 16B load). 8-row lookahead (two named register groups, statically
// rotated) = 8 NT loads in flight/thread (~32 KiB/CU at 1 block/CU); `live`
// mask handles the ci<0 prefix; ADV advances h at chunk boundaries.
__global__ __launch_bounds__(256)
void fused_kernel(const f4* __restrict__ x4,
                  const f4* __restrict__ res4,
                  const int* __restrict__ pos,
                  const float* __restrict__ dec,
                  const int* __restrict__ ci_tile,
                  const f4* __restrict__ hinit4,
                  f4* __restrict__ out4) {
    const int blk = blockIdx.x;          // b*NTILE_ + k
    const int b = blk >> 5;              // NTILE_ = 32
    const int k = blk & (NTILE_ - 1);
    const int t = threadIdx.x;
    const int l0 = k * TROWS_;

    const int m0 = (k == 0) ? -1 : ci_tile[b * NTILE_ + k];

    // boundary list for this tile: chunks m0+1 .. m0+TROWS_+1 (sentinel-padded)
    __shared__ int   pl[TROWS_ + 2];
    __shared__ float dl[TROWS_ + 2];
    for (int i = t; i < TROWS_ + 2; i += 256) {
        const int mm = m0 + 1 + i;
        if (mm < M_) {
            pl[i] = pos[(size_t)b * M_ + mm];
            dl[i] = dec[(size_t)b * M_ + mm];
        } else {
            pl[i] = L_;                  // sentinel: never matches a row
            dl[i] = 1.0f;
        }
    }
    __syncthreads();

    const f4* xrow = x4 + (size_t)b * L_ * D4_;

    f4 h = hinit4[(size_t)blk * D4_ + t];   // state entering this tile
    float live = (m0 >= 0) ? 1.0f : 0.0f;

    const f4* resrow = res4 + (size_t)b * L_ * D4_;
    f4*       outrow = out4 + (size_t)b * L_ * D4_;

    int mi = 0;
    int nextb = pl[0];
    int a0 = (pl[0] < L_) ? pl[0] : 0;
    int a1 = (pl[1] < L_) ? pl[1] : 0;
    f4 xn  = xrow[(size_t)a0 * D4_ + t];
    f4 xn2 = xrow[(size_t)a1 * D4_ + t];
    int l = l0;

    #define ADV(K, HH, LV)                                                \
        if (l + (K) == nextb) {                                           \
            const float d_ = dl[mi];                                      \
            h = d_ * h + (1.0f - d_) * xn;                                \
            live = 1.0f;                                                  \
            xn = xn2;                                                     \
            ++mi;                                                         \
            nextb = pl[mi];                                               \
            const int nr_ = (pl[mi + 1] < L_) ? pl[mi + 1] : 0;           \
            xn2 = xrow[(size_t)nr_ * D4_ + t];                            \
        }                                                                 \
        HH = h; LV = live;

    #define STORE4                                                        \
        {                                                                 \
            f4 h0, h1, h2, h3;                                            \
            float v0, v1, v2, v3;                                         \
            ADV(0, h0, v0); ADV(1, h1, v1); ADV(2, h2, v2); ADV(3, h3, v3);\
            __builtin_nontemporal_store(c0 + v0 * h0, outrow + (size_t)(l + 0) * D4_ + t); \
            __builtin_nontemporal_store(c1 + v1 * h1, outrow + (size_t)(l + 1) * D4_ + t); \
            __builtin_nontemporal_store(c2 + v2 * h2, outrow + (size_t)(l + 2) * D4_ + t); \
            __builtin_nontemporal_store(c3 + v3 * h3, outrow + (size_t)(l + 3) * D4_ + t); \
        }

    // prime: 8 rows of residual in flight
    f4 c0 = __builtin_nontemporal_load(resrow + (size_t)(l + 0) * D4_ + t);
    f4 c1 = __builtin_nontemporal_load(resrow + (size_t)(l + 1) * D4_ + t);
    f4 c2 = __builtin_nontemporal_load(resrow + (size_t)(l + 2) * D4_ + t);
    f4 c3 = __builtin_nontemporal_load(resrow + (size_t)(l + 3) * D4_ + t);
    f4 c4 = __builtin_nontemporal_load(resrow + (size_t)(l + 4) * D4_ + t);
    f4 c5 = __builtin_nontemporal_load(resrow + (size_t)(l + 5) * D4_ + t);
    f4 c6 = __builtin_nontemporal_load(resrow + (size_t)(l + 6) * D4_ + t);
    f4 c7 = __builtin_nontemporal_load(resrow + (size_t)(l + 7) * D4_ + t);

    // main: (TROWS_/4 - 2) groups with 8-row lookahead
    for (int g = 0; g < (TROWS_ / 4) - 2; ++g) {
        f4 n0 = __builtin_nontemporal_load(resrow + (size_t)(l +  8) * D4_ + t);
        f4 n1 = __builtin_nontemporal_load(resrow + (size_t)(l +  9) * D4_ + t);
        f4 n2 = __builtin_nontemporal_load(resrow + (size_t)(l + 10) * D4_ + t);
        f4 n3 = __builtin_nontemporal_load(resrow + (size_t)(l + 11) * D4_ + t);
        STORE4;
        c0 = c4; c1 = c5; c2 = c6; c3 = c7;
        c4 = n0; c5 = n1; c6 = n2; c7 = n3;
        l += 4;
    }
    // epilogue: last two groups
    STORE4;
    c0 = c4; c1 = c5; c2 = c6; c3 = c7;
    l += 4;
    STORE4;
    #undef STORE4
    #undef ADV
}

extern "C" void kernel_launch(void* const* d_in, const int* in_sizes, int n_in,
                              void* d_out, int out_size, void* d_ws, size_t ws_size,
                              hipStream_t stream) {
    const float* x        = (const float*)d_in[0];
    const float* residual = (const float*)d_in[1];
    const float* prob     = (const float*)d_in[2];
    const void*  mask     = d_in[3];
    const float* state    = (const float*)d_in[4];

    float* out       = (float*)d_out;                       // (B,L,D)
    float* new_state = out + (size_t)B_ * L_ * D_;          // (B,D)

    if (ws_size < WS_TOTAL) return;  // fail loudly (zeros) rather than corrupt

    char* ws = (char*)d_ws;
    int*   pos     = (int*)  (ws + OFF_POS);
    float* dec     = (float*)(ws + OFF_DEC);
    float* Aseg    = (float*)(ws + OFF_A);
    int*   ci_tile = (int*)  (ws + OFF_CIT);
    float* ez      = (float*)(ws + OFF_EZ);
    float* hinit   = (float*)(ws + OFF_HINIT);

    compact_kernel<<<B_, 1024, 0, stream>>>(mask, prob, pos, dec, ci_tile);

    segend_kernel<<<NBLK_, 256, 0, stream>>>(
        (const f4*)x, pos, dec, ci_tile, (f4*)ez, Aseg);

    combine_kernel<<<dim3(B_, 16), 64, 0, stream>>>(
        ez, Aseg, state, hinit, new_state);

    fused_kernel<<<NBLK_, 256, 0, stream>>>(
        (const f4*)x, (const f4*)residual, pos, dec, ci_tile,
        (const f4*)hinit, (f4*)out);
}

// Round 17
// 120.949 us; speedup vs baseline: 3.9783x; 1.0376x over previous
//
#include <hip/hip_runtime.h>
#include <stdint.h>
#include <stddef.h>

// Problem constants (from reference): B=8, L=8192, D=1024, M=L/4=2048.
// Setup guarantees exactly M true mask positions per row -> counts == M.
#define B_ 8
#define L_ 8192
#define D_ 1024
#define M_ 2048
#define D4_ (D_/4)
#define TROWS_ 256           // rows per tile (one row per thread in list build)
#define NTILE_ (L_/TROWS_)   // 32 tiles per batch row
#define NBLK_ (B_*NTILE_)    // 256 blocks (1 per CU)

typedef float f4 __attribute__((ext_vector_type(4)));

// ---------------- workspace layout (bytes) ----------------
#define OFF_FLAG   ((size_t)0)                               // int u8flag
#define OFF_A      ((size_t)256)                             // float A[NBLK]
#define OFF_CNT    (OFF_A    + (size_t)NBLK_*4)              // int cnt[NBLK]
#define OFF_LIVE   (OFF_CNT  + (size_t)NBLK_*4)              // int live[NBLK]
#define OFF_EZ     (OFF_LIVE + (size_t)NBLK_*4)              // float ez[NBLK][D]
#define OFF_HINIT  (OFF_EZ   + (size_t)NBLK_*D_*4)           // float hinit[NBLK][D]
#define WS_TOTAL   (OFF_HINIT + (size_t)NBLK_*D_*4)

// ---------------- kernel 1: per-tile list build + zero-init scan ------------
// One block per (b, tile k). Phase 1 (one ROW per thread): rebuild the tile's
// local chunk list from raw mask+prob via a block prefix sum. Phase 2 (one
// CHANNEL per thread): zero-init EMA scan over the tile's chunks -> segment
// end value ez, decay product A, count n. Mask dtype (u8 bool vs int32)
// detected per-block from the first 8 KiB; block 0 publishes it for fused.
__global__ __launch_bounds__(256)
void segend_kernel(const f4* __restrict__ x4,
                   const float* __restrict__ prob,
                   const void* __restrict__ mask_raw,
                   f4* __restrict__ ez4,
                   float* __restrict__ Aseg,
                   int* __restrict__ cnt,
                   int* __restrict__ u8out) {
    const int blk = blockIdx.x;          // b*NTILE_ + k
    const int b = blk >> 5;              // NTILE_ = 32
    const int k = blk & (NTILE_ - 1);
    const int t = threadIdx.x;
    const int l0 = k * TROWS_;

    __shared__ int   u8flag;
    __shared__ int   wsum[4];
    __shared__ int   pl[TROWS_ + 2];
    __shared__ float dl[TROWS_ + 2];

    if (t == 0) u8flag = 0;
    __syncthreads();
    {
        const uint32_t* mu = (const uint32_t*)mask_raw;
        uint32_t orv = 0;
        #pragma unroll
        for (int j = 0; j < 8; j++) orv |= mu[t * 8 + j];
        if (orv > 1u) atomicOr(&u8flag, 1);
    }
    pl[t] = L_; dl[t] = 1.0f;            // sentinel init
    if (t < 2) { pl[TROWS_ + t] = L_; dl[TROWS_ + t] = 1.0f; }
    __syncthreads();
    const bool u8 = (u8flag != 0);
    if (blk == 0 && t == 0) *u8out = u8 ? 1 : 0;

    // ---- phase 1: local chunk list (thread t owns row l0+t) ----
    const int gl = b * L_ + l0 + t;
    const int mv = u8 ? (((const uint8_t*)mask_raw)[gl] ? 1 : 0)
                      : (((const int*)mask_raw)[gl] ? 1 : 0);
    const float dv = fminf(fmaxf(1.0f - prob[gl], 0.0f), 1.0f);
    const int lane = t & 63, wid = t >> 6;
    int v = mv;
    #pragma unroll
    for (int off = 1; off < 64; off <<= 1) {
        int nn = __shfl_up(v, off, 64);
        if (lane >= off) v += nn;
    }
    if (lane == 63) wsum[wid] = v;
    __syncthreads();
    int acc = 0;
    #pragma unroll
    for (int w = 0; w < 4; w++) if (w < wid) acc += wsum[w];
    const int n = wsum[0] + wsum[1] + wsum[2] + wsum[3];
    const int excl = (v - mv) + acc;
    if (mv) { pl[excl] = l0 + t; dl[excl] = dv; }
    __syncthreads();

    // ---- phase 2: zero-init scan (thread t owns f4 channel t) ----
    f4 h = (f4)(0.0f);
    float A = 1.0f;
    const f4* xrow = x4 + (size_t)b * L_ * D4_;
    for (int g = 0; g < n; g += 8) {
        f4    xv[8];
        float dd[8];
        #pragma unroll
        for (int j = 0; j < 8; j++) {
            const int mm = g + j;
            const int mc = (mm < n) ? mm : 0;
            dd[j] = (mm < n) ? dl[mc] : 1.0f;
            xv[j] = xrow[(size_t)pl[mc] * D4_ + t];
        }
        #pragma unroll
        for (int j = 0; j < 8; j++) {
            h = dd[j] * h + (1.0f - dd[j]) * xv[j];
            A *= dd[j];
        }
    }
    ez4[(size_t)blk * D4_ + t] = h;
    if (t == 0) { Aseg[blk] = A; cnt[blk] = n; }
}

// ---------------- kernel 2: carry propagation across tiles + new_state ------
// grid (B, 16), block 64: scalar channel per thread (8192 parallel chains).
// hinit[b][k] = ema state ENTERING tile k (c_0 = state); live[b][k] = any
// chunk before tile k. ez prefetched in batches of 8.
__global__ __launch_bounds__(64)
void combine_kernel(const float* __restrict__ ez,
                    const float* __restrict__ Aseg,
                    const int* __restrict__ cnt,
                    const float* __restrict__ state,
                    float* __restrict__ hinit,
                    int* __restrict__ live,
                    float* __restrict__ newstate) {
    const int b = blockIdx.x;
    const int ch = blockIdx.y * 64 + threadIdx.x;   // scalar channel 0..1023
    __shared__ float Al[NTILE_];
    __shared__ int   Cl[NTILE_];
    if (threadIdx.x < NTILE_) {
        Al[threadIdx.x] = Aseg[b * NTILE_ + threadIdx.x];
        Cl[threadIdx.x] = cnt[b * NTILE_ + threadIdx.x];
    }
    __syncthreads();

    float c = state[(size_t)b * D_ + ch];
    for (int s0 = 0; s0 < NTILE_; s0 += 8) {
        float e[8];
        #pragma unroll
        for (int j = 0; j < 8; j++)
            e[j] = ez[((size_t)b * NTILE_ + s0 + j) * D_ + ch];
        #pragma unroll
        for (int j = 0; j < 8; j++) {
            hinit[((size_t)b * NTILE_ + s0 + j) * D_ + ch] = c;
            c = fmaf(Al[s0 + j], c, e[j]);
        }
    }
    newstate[(size_t)b * D_ + ch] = c;   // counts == M guaranteed
    if (blockIdx.y == 0 && threadIdx.x == 0) {
        int cc = 0;
        for (int kk = 0; kk < NTILE_; kk++) {
            live[b * NTILE_ + kk] = (cc > 0) ? 1 : 0;
            cc += Cl[kk];
        }
    }
}

// ---------------- kernel 3: PURE-STREAM fused scan + scatter (8-deep) -------
// One block per (b, tile). Rebuilds the tile's local chunk list (same prefix
// sum as segend), seeds h from hinit[b][k], live from live[b][k], then runs
// the fixed 256-row NT stream with 8-row lookahead; ADV advances h at chunk
// boundaries with double-prefetched x gathers (L3-hot from segend).
__global__ __launch_bounds__(256)
void fused_kernel(const f4* __restrict__ x4,
                  const f4* __restrict__ res4,
                  const float* __restrict__ prob,
                  const void* __restrict__ mask_raw,
                  const int* __restrict__ u8in,
                  const int* __restrict__ liveA,
                  const f4* __restrict__ hinit4,
                  f4* __restrict__ out4) {
    const int blk = blockIdx.x;          // b*NTILE_ + k
    const int b = blk >> 5;              // NTILE_ = 32
    const int k = blk & (NTILE_ - 1);
    const int t = threadIdx.x;
    const int l0 = k * TROWS_;

    __shared__ int   wsum[4];
    __shared__ int   pl[TROWS_ + 2];
    __shared__ float dl[TROWS_ + 2];

    pl[t] = L_; dl[t] = 1.0f;            // sentinel init
    if (t < 2) { pl[TROWS_ + t] = L_; dl[TROWS_ + t] = 1.0f; }
    const bool u8 = (*u8in != 0);        // uniform scalar load

    const int gl = b * L_ + l0 + t;
    const int mv = u8 ? (((const uint8_t*)mask_raw)[gl] ? 1 : 0)
                      : (((const int*)mask_raw)[gl] ? 1 : 0);
    const float dv = fminf(fmaxf(1.0f - prob[gl], 0.0f), 1.0f);
    const int lane = t & 63, wid = t >> 6;
    int v = mv;
    #pragma unroll
    for (int off = 1; off < 64; off <<= 1) {
        int nn = __shfl_up(v, off, 64);
        if (lane >= off) v += nn;
    }
    if (lane == 63) wsum[wid] = v;
    __syncthreads();                     // covers sentinel init + wsum
    int acc = 0;
    #pragma unroll
    for (int w = 0; w < 4; w++) if (w < wid) acc += wsum[w];
    const int excl = (v - mv) + acc;
    if (mv) { pl[excl] = l0 + t; dl[excl] = dv; }
    __syncthreads();

    const f4* xrow = x4 + (size_t)b * L_ * D4_;

    f4 h = hinit4[(size_t)blk * D4_ + t];   // state entering this tile
    float live = liveA[blk] ? 1.0f : 0.0f;

    const f4* resrow = res4 + (size_t)b * L_ * D4_;
    f4*       outrow = out4 + (size_t)b * L_ * D4_;

    int mi = 0;
    int nextb = pl[0];
    int a0 = (pl[0] < L_) ? pl[0] : 0;
    int a1 = (pl[1] < L_) ? pl[1] : 0;
    f4 xn  = xrow[(size_t)a0 * D4_ + t];
    f4 xn2 = xrow[(size_t)a1 * D4_ + t];
    int l = l0;

    #define ADV(K, HH, LV)                                                \
        if (l + (K) == nextb) {                                           \
            const float d_ = dl[mi];                                      \
            h = d_ * h + (1.0f - d_) * xn;                                \
            live = 1.0f;                                                  \
            xn = xn2;                                                     \
            ++mi;                                                         \
            nextb = pl[mi];                                               \
            const int nr_ = (pl[mi + 1] < L_) ? pl[mi + 1] : 0;           \
            xn2 = xrow[(size_t)nr_ * D4_ + t];                            \
        }                                                                 \
        HH = h; LV = live;

    #define STORE4                                                        \
        {                                                                 \
            f4 h0, h1, h2, h3;                                            \
            float v0, v1, v2, v3;                                         \
            ADV(0, h0, v0); ADV(1, h1, v1); ADV(2, h2, v2); ADV(3, h3, v3);\
            __builtin_nontemporal_store(c0 + v0 * h0, outrow + (size_t)(l + 0) * D4_ + t); \
            __builtin_nontemporal_store(c1 + v1 * h1, outrow + (size_t)(l + 1) * D4_ + t); \
            __builtin_nontemporal_store(c2 + v2 * h2, outrow + (size_t)(l + 2) * D4_ + t); \
            __builtin_nontemporal_store(c3 + v3 * h3, outrow + (size_t)(l + 3) * D4_ + t); \
        }

    // prime: 8 rows of residual in flight
    f4 c0 = __builtin_nontemporal_load(resrow + (size_t)(l + 0) * D4_ + t);
    f4 c1 = __builtin_nontemporal_load(resrow + (size_t)(l + 1) * D4_ + t);
    f4 c2 = __builtin_nontemporal_load(resrow + (size_t)(l + 2) * D4_ + t);
    f4 c3 = __builtin_nontemporal_load(resrow + (size_t)(l + 3) * D4_ + t);
    f4 c4 = __builtin_nontemporal_load(resrow + (size_t)(l + 4) * D4_ + t);
    f4 c5 = __builtin_nontemporal_load(resrow + (size_t)(l + 5) * D4_ + t);
    f4 c6 = __builtin_nontemporal_load(resrow + (size_t)(l + 6) * D4_ + t);
    f4 c7 = __builtin_nontemporal_load(resrow + (size_t)(l + 7) * D4_ + t);

    // main: (TROWS_/4 - 2) groups with 8-row lookahead
    for (int g = 0; g < (TROWS_ / 4) - 2; ++g) {
        f4 n0 = __builtin_nontemporal_load(resrow + (size_t)(l +  8) * D4_ + t);
        f4 n1 = __builtin_nontemporal_load(resrow + (size_t)(l +  9) * D4_ + t);
        f4 n2 = __builtin_nontemporal_load(resrow + (size_t)(l + 10) * D4_ + t);
        f4 n3 = __builtin_nontemporal_load(resrow + (size_t)(l + 11) * D4_ + t);
        STORE4;
        c0 = c4; c1 = c5; c2 = c6; c3 = c7;
        c4 = n0; c5 = n1; c6 = n2; c7 = n3;
        l += 4;
    }
    // epilogue: last two groups
    STORE4;
    c0 = c4; c1 = c5; c2 = c6; c3 = c7;
    l += 4;
    STORE4;
    #undef STORE4
    #undef ADV
}

extern "C" void kernel_launch(void* const* d_in, const int* in_sizes, int n_in,
                              void* d_out, int out_size, void* d_ws, size_t ws_size,
                              hipStream_t stream) {
    const float* x        = (const float*)d_in[0];
    const float* residual = (const float*)d_in[1];
    const float* prob     = (const float*)d_in[2];
    const void*  mask     = d_in[3];
    const float* state    = (const float*)d_in[4];

    float* out       = (float*)d_out;                       // (B,L,D)
    float* new_state = out + (size_t)B_ * L_ * D_;          // (B,D)

    if (ws_size < WS_TOTAL) return;  // fail loudly (zeros) rather than corrupt

    char* ws = (char*)d_ws;
    int*   u8flag = (int*)  (ws + OFF_FLAG);
    float* Aseg   = (float*)(ws + OFF_A);
    int*   cnt    = (int*)  (ws + OFF_CNT);
    int*   live   = (int*)  (ws + OFF_LIVE);
    float* ez     = (float*)(ws + OFF_EZ);
    float* hinit  = (float*)(ws + OFF_HINIT);

    segend_kernel<<<NBLK_, 256, 0, stream>>>(
        (const f4*)x, prob, mask, (f4*)ez, Aseg, cnt, u8flag);

    combine_kernel<<<dim3(B_, 16), 64, 0, stream>>>(
        ez, Aseg, cnt, state, hinit, live, new_state);

    fused_kernel<<<NBLK_, 256, 0, stream>>>(
        (const f4*)x, (const f4*)residual, prob, mask, u8flag, live,
        (const f4*)hinit, (f4*)out);
}